// Round 4
// baseline (682.774 us; speedup 1.0000x reference)
//
#include <hip/hip_runtime.h>
#include <hip/hip_bf16.h>
#include <stdint.h>

#define N_NODES 50000
#define N_EDGES 800000
#define NL 2

// K strides (bf16 elements)
#define KS1 296   // msg GEMM1: K=272 padded to 288 (9 k-steps), row stride 296
#define KS2 136   // 128-K GEMMs: 4 k-steps, stride 136
#define KSU 264   // upd GEMM1: K=256 (8 k-steps), stride 264

typedef __bf16 bf16x8 __attribute__((ext_vector_type(8)));
typedef float f32x4 __attribute__((ext_vector_type(4)));

__device__ __forceinline__ f32x4 mfma_bf16(uint4 a, uint4 b, f32x4 c) {
    return __builtin_amdgcn_mfma_f32_16x16x32_bf16(
        __builtin_bit_cast(bf16x8, a), __builtin_bit_cast(bf16x8, b), c, 0, 0, 0);
}

__device__ __forceinline__ unsigned short f2b(float f) {
    union { float f; unsigned u; } v; v.f = f;
    unsigned r = v.u + 0x7FFFu + ((v.u >> 16) & 1u);   // RNE
    return (unsigned short)(r >> 16);
}

// Per-wave 16-row x 128-col tile (head_kernel).
template<int KSTEPS, int BSTR>
__device__ __forceinline__ void gemm8(const unsigned short* aLane,
                                      const unsigned short* bLane, f32x4 acc[8]) {
#pragma unroll
    for (int kc = 0; kc < KSTEPS; kc++) {
        uint4 a = *(const uint4*)(aLane + kc * 32);
#pragma unroll
        for (int ct = 0; ct < 8; ct++) {
            uint4 b = *(const uint4*)(bLane + (size_t)ct * 16 * BSTR + kc * 32);
            acc[ct] = mfma_bf16(a, b, acc[ct]);
        }
    }
}

// Column-split wave tile: 64 rows (4 rt) x 32 cols (2 ct) per wave (upd_kernel).
template<int KSTEPS, int ASTR, int BSTR>
__device__ __forceinline__ void gemm_2x4(const unsigned short* aLane,
                                         const unsigned short* bLane,
                                         f32x4 acc[4][2]) {
#pragma unroll
    for (int kc = 0; kc < KSTEPS; kc++) {
        uint4 b0 = *(const uint4*)(bLane + kc * 32);
        uint4 b1 = *(const uint4*)(bLane + (size_t)16 * BSTR + kc * 32);
#pragma unroll
        for (int rt = 0; rt < 4; rt++) {
            uint4 a = *(const uint4*)(aLane + (size_t)rt * 16 * ASTR + kc * 32);
            acc[rt][0] = mfma_bf16(a, b0, acc[rt][0]);
            acc[rt][1] = mfma_bf16(a, b1, acc[rt][1]);
        }
    }
}

// ---------------- weight prep: transpose + pad + fp32->bf16 ----------------
// u1t k-range [128,256) is written by prep2_kernel (W2@U1b fold).
__global__ void prep_kernel(const float* __restrict__ mW1,
                            const float* __restrict__ uW1, const float* __restrict__ uW2,
                            const float* __restrict__ hW,
                            unsigned short* __restrict__ w1t,
                            unsigned short* __restrict__ u1t, unsigned short* __restrict__ u2t,
                            unsigned short* __restrict__ ht) {
    int i = blockIdx.x * 256 + threadIdx.x;
    const int S0 = NL * 128 * KS1;
    const int SU = NL * 128 * KSU;
    const int S3 = NL * 128 * KS2;
    const int S4 = 128 * KS2;
    if (i < S0) {
        int l = i / (128 * KS1), r = i % (128 * KS1), n = r / KS1, k = r % KS1;
        w1t[i] = (k < 272) ? f2b(mW1[((size_t)l * 272 + k) * 128 + n]) : (unsigned short)0;
        return;
    }
    i -= S0;
    if (i < SU) {
        int l = i / (128 * KSU), r = i % (128 * KSU), n = r / KSU, k = r % KSU;
        if (k < 128)       u1t[i] = f2b(uW1[((size_t)l * 256 + k) * 128 + n]);
        else if (k >= 256) u1t[i] = 0;
        // 128 <= k < 256: prep2 writes (W2@U1b)
        return;
    }
    i -= SU;
    if (i < S3) {
        int l = i / (128 * KS2), r = i % (128 * KS2), n = r / KS2, k = r % KS2;
        u2t[i] = (k < 128) ? f2b(uW2[((size_t)l * 128 + k) * 128 + n]) : (unsigned short)0;
        return;
    }
    i -= S3;
    if (i < S4) {
        int n = i / KS2, k = i % KS2;
        ht[i] = (k < 128) ? f2b(hW[(size_t)k * 128 + n]) : (unsigned short)0;
    }
}

// ---------------- prep2: u1t[l][n][128+j] = bf16( sum_c W2[l][j][c] * U1[l][128+c][n] )
__global__ void prep2_kernel(const float* __restrict__ mW2, const float* __restrict__ uW1,
                             unsigned short* __restrict__ u1t) {
    __shared__ float w2row[128];
    const int l = blockIdx.x >> 7, j = blockIdx.x & 127;
    const int n = threadIdx.x;
    w2row[n] = mW2[((size_t)l * 128 + j) * 128 + n];
    __syncthreads();
    float s = 0.f;
#pragma unroll 8
    for (int c = 0; c < 128; c++)
        s += w2row[c] * uW1[((size_t)l * 256 + 128 + c) * 128 + n];
    u1t[(size_t)l * 128 * KSU + (size_t)n * KSU + 128 + j] = f2b(s);
}

// ---------------- prep3: bfold[l][n] = sum_c b2[l][c] * U1[l][128+c][n]
__global__ void prep3_kernel(const float* __restrict__ mb2, const float* __restrict__ uW1,
                             float* __restrict__ bfold) {
    const int l = blockIdx.x;
    const int n = threadIdx.x;
    float s = 0.f;
#pragma unroll 8
    for (int c = 0; c < 128; c++)
        s += mb2[l * 128 + c] * uW1[((size_t)l * 256 + 128 + c) * 128 + n];
    bfold[l * 128 + n] = s;
}

// ---------------- encoder: relu(x@W+b) -> LN ----------------
__global__ __launch_bounds__(256) void enc_kernel(
        const float* __restrict__ x, const float* __restrict__ W,
        const float* __restrict__ b, const float* __restrict__ g, const float* __restrict__ bet,
        float* __restrict__ h, unsigned short* __restrict__ hb) {
    __shared__ float sx[64];
    __shared__ float redS[4], redSS[4];
    const int t = threadIdx.x;
    const int nb = blockIdx.x * 2;           // 2 nodes / block; 25000 blocks exact
    if (t < 64) sx[t] = x[(size_t)nb * 32 + t];
    __syncthreads();
    const int half = t >> 7, j = t & 127;
    const int node = nb + half;
    float acc = b[j];
#pragma unroll
    for (int k = 0; k < 32; k++) acc += sx[half * 32 + k] * W[k * 128 + j];
    float v = fmaxf(acc, 0.f);
    float s = v, ss = v * v;
#pragma unroll
    for (int d = 32; d > 0; d >>= 1) { s += __shfl_down(s, d); ss += __shfl_down(ss, d); }
    const int wv = t >> 6;
    if ((t & 63) == 0) { redS[wv] = s; redSS[wv] = ss; }
    __syncthreads();
    float S = redS[half * 2] + redS[half * 2 + 1];
    float SS = redSS[half * 2] + redSS[half * 2 + 1];
    float mu = S * (1.f / 128.f);
    float var = SS * (1.f / 128.f) - mu * mu;
    float rs = rsqrtf(var + 1e-5f);
    float o = (v - mu) * rs * g[j] + bet[j];
    h[(size_t)node * 128 + j] = o;
    hb[(size_t)node * 128 + j] = f2b(o);
}

// ---------------- counting sort of edges by target ----------------
__global__ void hist_kernel(const int* __restrict__ tgt, int* __restrict__ hist) {
    int i = blockIdx.x * 256 + threadIdx.x;   // E = 3125*256 exact
    atomicAdd(hist + tgt[i], 1);
}

__global__ void scan1_kernel(const int* __restrict__ hist, int* __restrict__ incl,
                             int* __restrict__ blksum) {
    __shared__ int buf[256];
    const int t = threadIdx.x;
    const int i = blockIdx.x * 256 + t;
    int v = (i < N_NODES) ? hist[i] : 0;
    buf[t] = v; __syncthreads();
#pragma unroll
    for (int d = 1; d < 256; d <<= 1) {
        int x = (t >= d) ? buf[t - d] : 0;
        __syncthreads();
        buf[t] += x;
        __syncthreads();
    }
    if (i < N_NODES) incl[i] = buf[t];
    if (t == 255) blksum[blockIdx.x] = buf[255];
}

__global__ void scan2_kernel(int* __restrict__ blksum, int nblk) {
    __shared__ int buf[256];
    const int t = threadIdx.x;
    int v = (t < nblk) ? blksum[t] : 0;
    buf[t] = v; __syncthreads();
#pragma unroll
    for (int d = 1; d < 256; d <<= 1) {
        int x = (t >= d) ? buf[t - d] : 0;
        __syncthreads();
        buf[t] += x;
        __syncthreads();
    }
    if (t < nblk) blksum[t] = buf[t];
}

__global__ void scan3_kernel(int* __restrict__ incl, const int* __restrict__ blksum,
                             const int* __restrict__ hist) {
    const int i = blockIdx.x * 256 + threadIdx.x;
    if (i >= N_NODES) return;
    const int b = blockIdx.x;
    const int base = (b > 0) ? blksum[b - 1] : 0;
    incl[i] = incl[i] + base - hist[i];
}

__global__ void scatter_kernel(const int* __restrict__ src, const int* __restrict__ tgt,
                               const float* __restrict__ ea, int* __restrict__ cursor,
                               unsigned short* __restrict__ sSrc, unsigned short* __restrict__ sTgt,
                               unsigned short* __restrict__ eabS) {
    const int e = blockIdx.x * 256 + threadIdx.x;   // E exact
    const int tg = tgt[e];
    const int p = atomicAdd(cursor + tg, 1);
    sSrc[p] = (unsigned short)src[e];
    sTgt[p] = (unsigned short)tg;
    const float4* s = (const float4*)(ea + (size_t)e * 16);
    ushort4* d = (ushort4*)(eabS + (size_t)p * 16);
#pragma unroll
    for (int i = 0; i < 4; i++) {
        float4 v = s[i];
        d[i] = make_ushort4(f2b(v.x), f2b(v.y), f2b(v.z), f2b(v.w));
    }
}

// ---------------- message GEMM1+relu + segmented relu-sum ----------------
// 128 edges/block, 4 waves; wave w owns cols [w*32,w*32+32) x all 128 rows
// (8 row-tiles, B register-reuse x8). GEMM2 is folded into upd (linearity).
// LDS phases on one 75,776-B buffer:
//   stage: bf16 [128][KS1]; relu out: fp32 [128][148] (148*4 == KS1*2).
__global__ __launch_bounds__(256, 2) void msg_kernel(
        const unsigned short* __restrict__ hb, const unsigned short* __restrict__ eabS,
        const unsigned short* __restrict__ sSrc, const unsigned short* __restrict__ sTgt,
        const unsigned short* __restrict__ w1t, const float* __restrict__ b1,
        float* __restrict__ aggr) {
    __shared__ __align__(16) unsigned short As[128 * KS1];
    __shared__ int sT[128];

    const int t = threadIdx.x;
    const int e0 = blockIdx.x * 128;         // E = 6250*128 exact
    {
        const int m = t >> 1, q = t & 1;     // 2 threads per edge
        const int pos = e0 + m;
        const int sn = sSrc[pos];
        const int tn = sTgt[pos];
        if (q == 0) sT[m] = tn;
        uint4* dst = (uint4*)(As + m * KS1);
        const uint4* pt = (const uint4*)(hb + (size_t)tn * 128);
        const uint4* ps = (const uint4*)(hb + (size_t)sn * 128);
#pragma unroll
        for (int i = 0; i < 8; i++) dst[q * 8 + i] = pt[q * 8 + i];
        uint4* dst2 = (uint4*)(As + m * KS1 + 128);
#pragma unroll
        for (int i = 0; i < 8; i++) dst2[q * 8 + i] = ps[q * 8 + i];
        if (q == 0) {
            const uint4* pe = (const uint4*)(eabS + (size_t)pos * 16);
            uint4* de = (uint4*)(As + m * KS1 + 256);
            de[0] = pe[0]; de[1] = pe[1];
        } else {
            uint4 z{0, 0, 0, 0};
            uint4* dp = (uint4*)(As + m * KS1 + 272);
            dp[0] = z; dp[1] = z;            // zero K 272..287 (288..295 never read)
        }
    }
    __syncthreads();

    const int wv = t >> 6, lane = t & 63, lr = lane & 15, lq = lane >> 4;
    const int cb = wv * 32;                  // this wave's column base
    const f32x4 z4 = {0.f, 0.f, 0.f, 0.f};

    f32x4 acc[8][2];
#pragma unroll
    for (int i = 0; i < 8; i++) { acc[i][0] = z4; acc[i][1] = z4; }
    {
        const unsigned short* aL = As + lr * KS1 + lq * 8;
        const unsigned short* bL = w1t + (size_t)(cb + lr) * KS1 + lq * 8;
#pragma unroll
        for (int kc = 0; kc < 9; kc++) {
            uint4 b0 = *(const uint4*)(bL + kc * 32);
            uint4 b1v = *(const uint4*)(bL + (size_t)16 * KS1 + kc * 32);
#pragma unroll
            for (int rt = 0; rt < 8; rt++) {
                uint4 a = *(const uint4*)(aL + (size_t)rt * 16 * KS1 + kc * 32);
                acc[rt][0] = mfma_bf16(a, b0, acc[rt][0]);
                acc[rt][1] = mfma_bf16(a, b1v, acc[rt][1]);
            }
        }
    }
    __syncthreads();                         // all GEMM1 A-reads complete

    // bias+relu -> fp32 [128][148] overlay
    float* Or = (float*)As;
#pragma unroll
    for (int ct = 0; ct < 2; ct++) {
        const int col = cb + ct * 16 + lr;
        const float bv = b1[col];
#pragma unroll
        for (int rt = 0; rt < 8; rt++) {
#pragma unroll
            for (int r = 0; r < 4; r++)
                Or[(size_t)(rt * 16 + lq * 4 + r) * 148 + col] = fmaxf(acc[rt][ct][r] + bv, 0.f);
        }
    }
    __syncthreads();

    // segmented reduction over sorted targets: 2 threads/col (64-row halves)
    {
        const int c = t >> 1;
        const int rbase = (t & 1) * 64;
        float s = 0.f;
        int cur = sT[rbase];
        for (int i = 0; i < 64; i++) {
            const int rg = rbase + i;
            const int tg = sT[rg];
            if (tg != cur) {
                atomicAdd(aggr + (size_t)cur * 128 + c, s);
                s = 0.f; cur = tg;
            }
            s += Or[(size_t)rg * 148 + c];
        }
        atomicAdd(aggr + (size_t)cur * 128 + c, s);
    }
}

// ---------------- update MLP + residual + LN ----------------
// aggr holds relu-sums; W2 is folded into u1t[128:256); bfold applied only
// where cnt>0 (b2 cancels for isolated nodes).
__global__ __launch_bounds__(256, 4) void upd_kernel(
        const unsigned short* __restrict__ hb_in, const float* __restrict__ h_in,
        const float* __restrict__ aggr, const int* __restrict__ hist,
        const unsigned short* __restrict__ u1t, const unsigned short* __restrict__ u2t,
        const float* __restrict__ b1, const float* __restrict__ bf,
        const float* __restrict__ b2,
        const float* __restrict__ g, const float* __restrict__ bet,
        float* __restrict__ h_out, unsigned short* __restrict__ hb_out) {
    __shared__ __align__(16) char smemA[64 * KSU * 2];
    __shared__ float sF[64];
    unsigned short* As = (unsigned short*)smemA;
    float* LNb = (float*)smemA;

    const int t = threadIdx.x;
    const int n0 = blockIdx.x * 64;
    {
        const int m = t >> 2, q = t & 3;
        const int node = n0 + m;
        unsigned short* row = As + m * KSU;
        if (node < N_NODES) {
            const uint4* ph = (const uint4*)(hb_in + (size_t)node * 128);
            uint4* d0 = (uint4*)row;
#pragma unroll
            for (int i = 0; i < 4; i++) d0[q * 4 + i] = ph[q * 4 + i];
            const int cntv = hist[node];
            if (q == 0) sF[m] = (cntv > 0) ? 1.f : 0.f;
            const float rden = 1.0f / fmaxf((float)cntv, 1.0f);
            const float4* pa = (const float4*)(aggr + (size_t)node * 128 + q * 32);
            ushort4* d1 = (ushort4*)(row + 128 + q * 32);
#pragma unroll
            for (int i = 0; i < 8; i++) {
                float4 v = pa[i];
                d1[i] = make_ushort4(f2b(v.x * rden), f2b(v.y * rden),
                                     f2b(v.z * rden), f2b(v.w * rden));
            }
            if (q == 0) { uint4 z{0, 0, 0, 0}; ((uint4*)(row + 256))[0] = z; }
        } else {
            if (q == 0) sF[m] = 0.f;
            uint4 z{0, 0, 0, 0};
            uint4* d = (uint4*)row;
            for (int i = q; i < 33; i += 4) d[i] = z;
        }
    }
    __syncthreads();

    const int wv = t >> 6, lane = t & 63, lr = lane & 15, lq = lane >> 4;
    const int cb = wv * 32;
    const f32x4 z4 = {0.f, 0.f, 0.f, 0.f};

    f32x4 acc[4][2];
#pragma unroll
    for (int i = 0; i < 4; i++) { acc[i][0] = z4; acc[i][1] = z4; }
    gemm_2x4<8, KSU, KSU>(As + lr * KSU + lq * 8,
                          u1t + (size_t)(cb + lr) * KSU + lq * 8, acc);
    __syncthreads();

#pragma unroll
    for (int ct = 0; ct < 2; ct++) {
        const int col = cb + ct * 16 + lr;
        const float bv = b1[col];
        const float bfv = bf[col];
#pragma unroll
        for (int rt = 0; rt < 4; rt++) {
#pragma unroll
            for (int r = 0; r < 4; r++) {
                const int ml = rt * 16 + lq * 4 + r;
                float v = fmaxf(acc[rt][ct][r] + bv + sF[ml] * bfv, 0.f);
                As[ml * KSU + col] = f2b(v);
            }
        }
    }
    __syncthreads();

    f32x4 acc2[4][2];
#pragma unroll
    for (int i = 0; i < 4; i++) { acc2[i][0] = z4; acc2[i][1] = z4; }
    gemm_2x4<4, KSU, KS2>(As + lr * KSU + lq * 8,
                          u2t + (size_t)(cb + lr) * KS2 + lq * 8, acc2);
    __syncthreads();

    // residual add into LN staging fp32 [64][132]
#pragma unroll
    for (int ct = 0; ct < 2; ct++) {
        const int col = cb + ct * 16 + lr;
        const float bv = b2[col];
#pragma unroll
        for (int rt = 0; rt < 4; rt++) {
#pragma unroll
            for (int r = 0; r < 4; r++) {
                const int ml = rt * 16 + lq * 4 + r;
                const int node = n0 + ml;
                if (node < N_NODES)
                    LNb[ml * 132 + col] = acc2[rt][ct][r] + bv + h_in[(size_t)node * 128 + col];
            }
        }
    }
    __syncthreads();

    {   // LayerNorm: 4 threads per row
        const int r = t >> 2, c0 = (t & 3) * 32;
        const int node = n0 + r;
        if (node < N_NODES) {
            float s = 0.f, ss = 0.f;
#pragma unroll
            for (int i = 0; i < 32; i++) { float v = LNb[r * 132 + c0 + i]; s += v; ss += v * v; }
            s += __shfl_xor(s, 1); ss += __shfl_xor(ss, 1);
            s += __shfl_xor(s, 2); ss += __shfl_xor(ss, 2);
            const float mu = s * (1.0f / 128.0f);
            const float var = ss * (1.0f / 128.0f) - mu * mu;
            const float rs = rsqrtf(var + 1e-5f);
#pragma unroll
            for (int i = 0; i < 32; i++) {
                const int j = c0 + i;
                float v = (LNb[r * 132 + j] - mu) * rs * g[j] + bet[j];
                h_out[(size_t)node * 128 + j] = v;
                hb_out[(size_t)node * 128 + j] = f2b(v);
            }
        }
    }
}

// ---------------- head GEMM ----------------
__global__ __launch_bounds__(256, 2) void head_kernel(
        const unsigned short* __restrict__ hb, const unsigned short* __restrict__ ht,
        const float* __restrict__ hbias, float* __restrict__ out) {
    __shared__ __align__(16) unsigned short As[64 * KS2];
    const int t = threadIdx.x;
    const int n0 = blockIdx.x * 64;
    {
        const int m = t >> 2, q = t & 3;
        const int node = n0 + m;
        uint4* dst = (uint4*)(As + m * KS2);
        if (node < N_NODES) {
            const uint4* s = (const uint4*)(hb + (size_t)node * 128);
#pragma unroll
            for (int i = 0; i < 4; i++) dst[q * 4 + i] = s[q * 4 + i];
        } else {
            uint4 z{0, 0, 0, 0};
            for (int i = q; i < 16; i += 4) dst[i] = z;
        }
    }
    __syncthreads();

    const int wv = t >> 6, lane = t & 63, lr = lane & 15, lq = lane >> 4;
    const int m0 = wv * 16;
    const f32x4 z4 = {0.f, 0.f, 0.f, 0.f};
    f32x4 acc[8];
#pragma unroll
    for (int i = 0; i < 8; i++) acc[i] = z4;
    gemm8<4, KS2>(As + (m0 + lr) * KS2 + lq * 8, ht + (size_t)lr * KS2 + lq * 8, acc);
#pragma unroll
    for (int ct = 0; ct < 8; ct++) {
        const int col = ct * 16 + lr;
        const float bv = hbias[col];
#pragma unroll
        for (int r = 0; r < 4; r++) {
            const int node = n0 + m0 + lq * 4 + r;
            if (node < N_NODES) out[(size_t)node * 128 + col] = acc[ct][r] + bv;
        }
    }
}

extern "C" void kernel_launch(void* const* d_in, const int* in_sizes, int n_in,
                              void* d_out, int out_size, void* d_ws, size_t ws_size,
                              hipStream_t stream) {
    const float* x       = (const float*)d_in[0];
    const int*   ei      = (const int*)d_in[1];
    const float* ea      = (const float*)d_in[2];
    const float* encW    = (const float*)d_in[3];
    const float* encb    = (const float*)d_in[4];
    const float* encg    = (const float*)d_in[5];
    const float* encbeta = (const float*)d_in[6];
    const float* msgW1   = (const float*)d_in[7];
    const float* msgb1   = (const float*)d_in[8];
    const float* msgW2   = (const float*)d_in[9];
    const float* msgb2   = (const float*)d_in[10];
    const float* updW1   = (const float*)d_in[11];
    const float* updb1   = (const float*)d_in[12];
    const float* updW2   = (const float*)d_in[13];
    const float* updb2   = (const float*)d_in[14];
    const float* lng     = (const float*)d_in[15];
    const float* lnbeta  = (const float*)d_in[16];
    const float* headW   = (const float*)d_in[17];
    const float* headb   = (const float*)d_in[18];

    char* w = (char*)d_ws;
    size_t off = 0;
    auto nxt = [&](size_t bytes) -> void* {
        void* p = w + off;
        off = (off + bytes + 255) & ~(size_t)255;
        return p;
    };
    float*          h     = (float*)nxt((size_t)N_NODES * 128 * 4);
    unsigned short* hb    = (unsigned short*)nxt((size_t)N_NODES * 128 * 2);
    float*          aggr  = (float*)nxt((size_t)N_NODES * 128 * 4);
    unsigned short* eabS  = (unsigned short*)nxt((size_t)N_EDGES * 16 * 2);
    unsigned short* sSrc  = (unsigned short*)nxt((size_t)N_EDGES * 2);
    unsigned short* sTgtS = (unsigned short*)nxt((size_t)N_EDGES * 2);
    int*            hist  = (int*)nxt((size_t)N_NODES * 4);
    int*            incl  = (int*)nxt((size_t)N_NODES * 4);   // becomes cursor
    int*            blksum= (int*)nxt(256 * 4);
    unsigned short* w1t   = (unsigned short*)nxt((size_t)NL * 128 * KS1 * 2);
    unsigned short* u1t   = (unsigned short*)nxt((size_t)NL * 128 * KSU * 2);
    unsigned short* u2t   = (unsigned short*)nxt((size_t)NL * 128 * KS2 * 2);
    unsigned short* ht    = (unsigned short*)nxt((size_t)128 * KS2 * 2);
    float*          bfold = (float*)nxt((size_t)NL * 128 * 4);

    const int NBLK = (N_NODES + 255) / 256;   // 196
    const int PREP_N = NL * 128 * KS1 + NL * 128 * KSU + NL * 128 * KS2 + 128 * KS2;

    hipMemsetAsync(hist, 0, (size_t)N_NODES * 4, stream);
    prep_kernel<<<(PREP_N + 255) / 256, 256, 0, stream>>>(msgW1, updW1, updW2, headW,
                                                          w1t, u1t, u2t, ht);
    prep2_kernel<<<NL * 128, 128, 0, stream>>>(msgW2, updW1, u1t);
    prep3_kernel<<<NL, 128, 0, stream>>>(msgb2, updW1, bfold);
    enc_kernel<<<25000, 256, 0, stream>>>(x, encW, encb, encg, encbeta, h, hb);
    hist_kernel<<<3125, 256, 0, stream>>>(ei + N_EDGES, hist);
    scan1_kernel<<<NBLK, 256, 0, stream>>>(hist, incl, blksum);
    scan2_kernel<<<1, 256, 0, stream>>>(blksum, NBLK);
    scan3_kernel<<<NBLK, 256, 0, stream>>>(incl, blksum, hist);
    scatter_kernel<<<3125, 256, 0, stream>>>(ei, ei + N_EDGES, ea, incl,
                                             sSrc, sTgtS, eabS);

    for (int l = 0; l < NL; l++) {
        hipMemsetAsync(aggr, 0, (size_t)N_NODES * 128 * 4, stream);
        msg_kernel<<<6250, 256, 0, stream>>>(hb, eabS, sSrc, sTgtS,
                                             w1t + (size_t)l * 128 * KS1,
                                             msgb1 + l * 128, aggr);
        upd_kernel<<<782, 256, 0, stream>>>(hb, h, aggr, hist,
                                            u1t + (size_t)l * 128 * KSU,
                                            u2t + (size_t)l * 128 * KS2,
                                            updb1 + l * 128, bfold + l * 128,
                                            updb2 + l * 128,
                                            lng + l * 128, lnbeta + l * 128, h, hb);
    }
    head_kernel<<<782, 256, 0, stream>>>(hb, ht, headb, (float*)d_out);
}

// Round 5
// 583.427 us; speedup vs baseline: 1.1703x; 1.1703x over previous
//
#include <hip/hip_runtime.h>
#include <hip/hip_bf16.h>
#include <stdint.h>

#define N_NODES 50000
#define N_EDGES 800000
#define NL 2

// K strides (bf16 elements)
#define KS2 136   // 128-K GEMMs: 4 k-steps, stride 136
#define KSU 264   // upd GEMM1: K=256 (8 k-steps), stride 264

typedef __bf16 bf16x8 __attribute__((ext_vector_type(8)));
typedef float f32x4 __attribute__((ext_vector_type(4)));

__device__ __forceinline__ f32x4 mfma_bf16(uint4 a, uint4 b, f32x4 c) {
    return __builtin_amdgcn_mfma_f32_16x16x32_bf16(
        __builtin_bit_cast(bf16x8, a), __builtin_bit_cast(bf16x8, b), c, 0, 0, 0);
}

__device__ __forceinline__ unsigned short f2b(float f) {
    union { float f; unsigned u; } v; v.f = f;
    unsigned r = v.u + 0x7FFFu + ((v.u >> 16) & 1u);   // RNE
    return (unsigned short)(r >> 16);
}

__device__ __forceinline__ float b2f(unsigned short u) {
    union { unsigned u; float f; } v; v.u = ((unsigned)u) << 16; return v.f;
}

// Per-wave 16-row x 128-col tile (head_kernel).
template<int KSTEPS, int BSTR>
__device__ __forceinline__ void gemm8(const unsigned short* aLane,
                                      const unsigned short* bLane, f32x4 acc[8]) {
#pragma unroll
    for (int kc = 0; kc < KSTEPS; kc++) {
        uint4 a = *(const uint4*)(aLane + kc * 32);
#pragma unroll
        for (int ct = 0; ct < 8; ct++) {
            uint4 b = *(const uint4*)(bLane + (size_t)ct * 16 * BSTR + kc * 32);
            acc[ct] = mfma_bf16(a, b, acc[ct]);
        }
    }
}

// Column-split wave tile: 64 rows (4 rt) x 32 cols (2 ct) per wave (upd_kernel).
template<int KSTEPS, int ASTR, int BSTR>
__device__ __forceinline__ void gemm_2x4(const unsigned short* aLane,
                                         const unsigned short* bLane,
                                         f32x4 acc[4][2]) {
#pragma unroll
    for (int kc = 0; kc < KSTEPS; kc++) {
        uint4 b0 = *(const uint4*)(bLane + kc * 32);
        uint4 b1 = *(const uint4*)(bLane + (size_t)16 * BSTR + kc * 32);
#pragma unroll
        for (int rt = 0; rt < 4; rt++) {
            uint4 a = *(const uint4*)(aLane + (size_t)rt * 16 * ASTR + kc * 32);
            acc[rt][0] = mfma_bf16(a, b0, acc[rt][0]);
            acc[rt][1] = mfma_bf16(a, b1, acc[rt][1]);
        }
    }
}

// ---------------- weight prep ----------------
// wab[l][j][k] (j<128: W1a^T for T; j>=128: W1b^T for S), stride 136, k<128.
// w1cp[l][j][k] = W1c^T zero-padded K=16->32.
// u1t k-range [128,256) written by prep2 (W2@U1b fold).
__global__ void prep_kernel(const float* __restrict__ mW1,
                            const float* __restrict__ uW1, const float* __restrict__ uW2,
                            const float* __restrict__ hW,
                            unsigned short* __restrict__ wab, unsigned short* __restrict__ w1cp,
                            unsigned short* __restrict__ u1t, unsigned short* __restrict__ u2t,
                            unsigned short* __restrict__ ht) {
    int i = blockIdx.x * 256 + threadIdx.x;
    const int SA = NL * 256 * 136;
    const int SC = NL * 128 * 32;
    const int SU = NL * 128 * KSU;
    const int S3 = NL * 128 * KS2;
    const int S4 = 128 * KS2;
    if (i < SA) {
        int l = i / (256 * 136), r = i % (256 * 136), j = r / 136, k = r % 136;
        float v = 0.f;
        if (k < 128)
            v = (j < 128) ? mW1[((size_t)l * 272 + k) * 128 + j]
                          : mW1[((size_t)l * 272 + 128 + k) * 128 + (j - 128)];
        wab[i] = f2b(v);
        return;
    }
    i -= SA;
    if (i < SC) {
        int l = i / (128 * 32), r = i % (128 * 32), j = r / 32, k = r % 32;
        w1cp[i] = (k < 16) ? f2b(mW1[((size_t)l * 272 + 256 + k) * 128 + j]) : (unsigned short)0;
        return;
    }
    i -= SC;
    if (i < SU) {
        int l = i / (128 * KSU), r = i % (128 * KSU), n = r / KSU, k = r % KSU;
        if (k < 128)       u1t[i] = f2b(uW1[((size_t)l * 256 + k) * 128 + n]);
        else if (k >= 256) u1t[i] = 0;
        return;
    }
    i -= SU;
    if (i < S3) {
        int l = i / (128 * KS2), r = i % (128 * KS2), n = r / KS2, k = r % KS2;
        u2t[i] = (k < 128) ? f2b(uW2[((size_t)l * 128 + k) * 128 + n]) : (unsigned short)0;
        return;
    }
    i -= S3;
    if (i < S4) {
        int n = i / KS2, k = i % KS2;
        ht[i] = (k < 128) ? f2b(hW[(size_t)k * 128 + n]) : (unsigned short)0;
    }
}

// ---------------- prep2: u1t[l][n][128+j] = bf16( sum_c W2[l][j][c] * U1[l][128+c][n] )
__global__ void prep2_kernel(const float* __restrict__ mW2, const float* __restrict__ uW1,
                             unsigned short* __restrict__ u1t) {
    __shared__ float w2row[128];
    const int l = blockIdx.x >> 7, j = blockIdx.x & 127;
    const int n = threadIdx.x;
    w2row[n] = mW2[((size_t)l * 128 + j) * 128 + n];
    __syncthreads();
    float s = 0.f;
#pragma unroll 8
    for (int c = 0; c < 128; c++)
        s += w2row[c] * uW1[((size_t)l * 256 + 128 + c) * 128 + n];
    u1t[(size_t)l * 128 * KSU + (size_t)n * KSU + 128 + j] = f2b(s);
}

// ---------------- prep3: bfold[l][n] = sum_c b2[l][c] * U1[l][128+c][n]
__global__ void prep3_kernel(const float* __restrict__ mb2, const float* __restrict__ uW1,
                             float* __restrict__ bfold) {
    const int l = blockIdx.x;
    const int n = threadIdx.x;
    float s = 0.f;
#pragma unroll 8
    for (int c = 0; c < 128; c++)
        s += mb2[l * 128 + c] * uW1[((size_t)l * 256 + 128 + c) * 128 + n];
    bfold[l * 128 + n] = s;
}

// ---------------- encoder: relu(x@W+b) -> LN ----------------
__global__ __launch_bounds__(256) void enc_kernel(
        const float* __restrict__ x, const float* __restrict__ W,
        const float* __restrict__ b, const float* __restrict__ g, const float* __restrict__ bet,
        float* __restrict__ h, unsigned short* __restrict__ hb) {
    __shared__ float sx[64];
    __shared__ float redS[4], redSS[4];
    const int t = threadIdx.x;
    const int nb = blockIdx.x * 2;           // 2 nodes / block; 25000 blocks exact
    if (t < 64) sx[t] = x[(size_t)nb * 32 + t];
    __syncthreads();
    const int half = t >> 7, j = t & 127;
    const int node = nb + half;
    float acc = b[j];
#pragma unroll
    for (int k = 0; k < 32; k++) acc += sx[half * 32 + k] * W[k * 128 + j];
    float v = fmaxf(acc, 0.f);
    float s = v, ss = v * v;
#pragma unroll
    for (int d = 32; d > 0; d >>= 1) { s += __shfl_down(s, d); ss += __shfl_down(ss, d); }
    const int wv = t >> 6;
    if ((t & 63) == 0) { redS[wv] = s; redSS[wv] = ss; }
    __syncthreads();
    float S = redS[half * 2] + redS[half * 2 + 1];
    float SS = redSS[half * 2] + redSS[half * 2 + 1];
    float mu = S * (1.f / 128.f);
    float var = SS * (1.f / 128.f) - mu * mu;
    float rs = rsqrtf(var + 1e-5f);
    float o = (v - mu) * rs * g[j] + bet[j];
    h[(size_t)node * 128 + j] = o;
    hb[(size_t)node * 128 + j] = f2b(o);
}

// ---------------- counting sort of edges by target ----------------
__global__ void hist_kernel(const int* __restrict__ tgt, int* __restrict__ hist) {
    int i = blockIdx.x * 256 + threadIdx.x;   // E = 3125*256 exact
    atomicAdd(hist + tgt[i], 1);
}

__global__ void scan1_kernel(const int* __restrict__ hist, int* __restrict__ incl,
                             int* __restrict__ blksum) {
    __shared__ int buf[256];
    const int t = threadIdx.x;
    const int i = blockIdx.x * 256 + t;
    int v = (i < N_NODES) ? hist[i] : 0;
    buf[t] = v; __syncthreads();
#pragma unroll
    for (int d = 1; d < 256; d <<= 1) {
        int x = (t >= d) ? buf[t - d] : 0;
        __syncthreads();
        buf[t] += x;
        __syncthreads();
    }
    if (i < N_NODES) incl[i] = buf[t];
    if (t == 255) blksum[blockIdx.x] = buf[255];
}

__global__ void scan2_kernel(int* __restrict__ blksum, int nblk) {
    __shared__ int buf[256];
    const int t = threadIdx.x;
    int v = (t < nblk) ? blksum[t] : 0;
    buf[t] = v; __syncthreads();
#pragma unroll
    for (int d = 1; d < 256; d <<= 1) {
        int x = (t >= d) ? buf[t - d] : 0;
        __syncthreads();
        buf[t] += x;
        __syncthreads();
    }
    if (t < nblk) blksum[t] = buf[t];
}

__global__ void scan3_kernel(int* __restrict__ incl, const int* __restrict__ blksum,
                             const int* __restrict__ hist) {
    const int i = blockIdx.x * 256 + threadIdx.x;
    if (i >= N_NODES) return;
    const int b = blockIdx.x;
    const int base = (b > 0) ? blksum[b - 1] : 0;
    incl[i] = incl[i] + base - hist[i];
}

__global__ void scatter_kernel(const int* __restrict__ src, const int* __restrict__ tgt,
                               const float* __restrict__ ea, int* __restrict__ cursor,
                               unsigned short* __restrict__ sSrc, unsigned short* __restrict__ sTgt,
                               unsigned short* __restrict__ eabS) {
    const int e = blockIdx.x * 256 + threadIdx.x;   // E exact
    const int tg = tgt[e];
    const int p = atomicAdd(cursor + tg, 1);
    sSrc[p] = (unsigned short)src[e];
    sTgt[p] = (unsigned short)tg;
    const float4* s = (const float4*)(ea + (size_t)e * 16);
    ushort4* d = (ushort4*)(eabS + (size_t)p * 16);
#pragma unroll
    for (int i = 0; i < 4; i++) {
        float4 v = s[i];
        d[i] = make_ushort4(f2b(v.x), f2b(v.y), f2b(v.z), f2b(v.w));
    }
}

// ---------------- per-layer node GEMM: T = h@W1a + b1, S = h@W1b ----------------
// 64 nodes/block, 4 waves col-split over 256 output cols (waves 0,1 -> T; 2,3 -> S).
__global__ __launch_bounds__(256, 4) void node_kernel(
        const unsigned short* __restrict__ hb, const unsigned short* __restrict__ wab,
        const float* __restrict__ b1,
        unsigned short* __restrict__ Tb, unsigned short* __restrict__ Sb) {
    __shared__ __align__(16) unsigned short As[64 * KS2];
    const int t = threadIdx.x;
    const int n0 = blockIdx.x * 64;
    {
        const int m = t >> 2, q = t & 3;
        const int node = n0 + m;
        uint4* dst = (uint4*)(As + m * KS2);
        if (node < N_NODES) {
            const uint4* s = (const uint4*)(hb + (size_t)node * 128);
#pragma unroll
            for (int i = 0; i < 4; i++) dst[q * 4 + i] = s[q * 4 + i];
        } else {
            uint4 z{0, 0, 0, 0};
            for (int i = q; i < 16; i += 4) dst[i] = z;
        }
    }
    __syncthreads();

    const int wv = t >> 6, lane = t & 63, lr = lane & 15, lq = lane >> 4;
    const int cb = wv * 64;
    const f32x4 z4 = {0.f, 0.f, 0.f, 0.f};
    f32x4 acc[4][4];                     // [rt][ct]
#pragma unroll
    for (int i = 0; i < 4; i++)
#pragma unroll
        for (int j = 0; j < 4; j++) acc[i][j] = z4;

    const unsigned short* aL = As + lr * KS2 + lq * 8;
    const unsigned short* bL = wab + (size_t)(cb + lr) * KS2 + lq * 8;
#pragma unroll
    for (int kc = 0; kc < 4; kc++) {
        uint4 bA = *(const uint4*)(bL + kc * 32);
        uint4 bB = *(const uint4*)(bL + (size_t)16 * KS2 + kc * 32);
        uint4 bC = *(const uint4*)(bL + (size_t)32 * KS2 + kc * 32);
        uint4 bD = *(const uint4*)(bL + (size_t)48 * KS2 + kc * 32);
#pragma unroll
        for (int rt = 0; rt < 4; rt++) {
            uint4 a = *(const uint4*)(aL + (size_t)rt * 16 * KS2 + kc * 32);
            acc[rt][0] = mfma_bf16(a, bA, acc[rt][0]);
            acc[rt][1] = mfma_bf16(a, bB, acc[rt][1]);
            acc[rt][2] = mfma_bf16(a, bC, acc[rt][2]);
            acc[rt][3] = mfma_bf16(a, bD, acc[rt][3]);
        }
    }
#pragma unroll
    for (int ct = 0; ct < 4; ct++) {
        const int j = cb + ct * 16 + lr;
        const float bias = (j < 128) ? b1[j] : 0.f;
#pragma unroll
        for (int rt = 0; rt < 4; rt++) {
#pragma unroll
            for (int r = 0; r < 4; r++) {
                const int node = n0 + rt * 16 + lq * 4 + r;
                if (node < N_NODES) {
                    const float v = acc[rt][ct][r] + bias;
                    if (j < 128) Tb[(size_t)node * 128 + j] = f2b(v);
                    else         Sb[(size_t)node * 128 + (j - 128)] = f2b(v);
                }
            }
        }
    }
}

// ---------------- edge kernel: relu(T[tgt]+S[src]+ea@W1c) + segmented sum ----------------
// 128 edges/block, 4 waves edge-split (2 row-tiles each). A-fragments loaded
// DIRECTLY from global eabS (no staging). One tiny K=32 MFMA step per rt.
__global__ __launch_bounds__(256, 4) void edge_kernel(
        const unsigned short* __restrict__ eabS,
        const unsigned short* __restrict__ sSrc, const unsigned short* __restrict__ sTgt,
        const unsigned short* __restrict__ w1cp,
        const unsigned short* __restrict__ Tb, const unsigned short* __restrict__ Sb,
        float* __restrict__ aggr) {
    __shared__ __align__(16) unsigned short Or[128 * 136];
    __shared__ int sT[128];
    __shared__ int sS[128];

    const int t = threadIdx.x;
    const int e0 = blockIdx.x * 128;         // E = 6250*128 exact
    if (t < 128) { sT[t] = sTgt[e0 + t]; sS[t] = sSrc[e0 + t]; }
    __syncthreads();

    const int wv = t >> 6, lane = t & 63, lr = lane & 15, lq = lane >> 4;
    const f32x4 z4 = {0.f, 0.f, 0.f, 0.f};
#pragma unroll
    for (int rh = 0; rh < 2; rh++) {
        const int rt = wv * 2 + rh;
        uint4 a = {0, 0, 0, 0};
        if (lq < 2) a = *(const uint4*)(eabS + (size_t)(e0 + rt * 16 + lr) * 16 + lq * 8);
        f32x4 acc[8];
#pragma unroll
        for (int ct = 0; ct < 8; ct++) {
            uint4 b = *(const uint4*)(w1cp + (ct * 16 + lr) * 32 + lq * 8);
            acc[ct] = mfma_bf16(a, b, z4);
        }
        // epilogue: + T'[tgt] + S[src], relu, bf16 -> LDS
#pragma unroll
        for (int ct = 0; ct < 8; ct++) {
            const int col = ct * 16 + lr;
#pragma unroll
            for (int r = 0; r < 4; r++) {
                const int row = rt * 16 + lq * 4 + r;
                const float tv = b2f(Tb[(size_t)sT[row] * 128 + col]);
                const float sv = b2f(Sb[(size_t)sS[row] * 128 + col]);
                Or[row * 136 + col] = f2b(fmaxf(acc[ct][r] + tv + sv, 0.f));
            }
        }
    }
    __syncthreads();

    // segmented sum over sorted targets: 2 threads/col (64-row halves), pure LDS
    {
        const int c = t >> 1;
        const int rb = (t & 1) * 64;
        float s = 0.f;
        int cur = sT[rb];
        for (int i = 0; i < 64; i++) {
            const int rg = rb + i;
            const int tg = sT[rg];
            if (tg != cur) {
                atomicAdd(aggr + (size_t)cur * 128 + c, s);
                s = 0.f; cur = tg;
            }
            s += b2f(Or[rg * 136 + c]);
        }
        atomicAdd(aggr + (size_t)cur * 128 + c, s);
    }
}

// ---------------- update MLP + residual + LN ----------------
__global__ __launch_bounds__(256, 4) void upd_kernel(
        const unsigned short* __restrict__ hb_in, const float* __restrict__ h_in,
        const float* __restrict__ aggr, const int* __restrict__ hist,
        const unsigned short* __restrict__ u1t, const unsigned short* __restrict__ u2t,
        const float* __restrict__ b1, const float* __restrict__ bf,
        const float* __restrict__ b2,
        const float* __restrict__ g, const float* __restrict__ bet,
        float* __restrict__ h_out, unsigned short* __restrict__ hb_out) {
    __shared__ __align__(16) char smemA[64 * KSU * 2];
    __shared__ float sF[64];
    unsigned short* As = (unsigned short*)smemA;
    float* LNb = (float*)smemA;

    const int t = threadIdx.x;
    const int n0 = blockIdx.x * 64;
    {
        const int m = t >> 2, q = t & 3;
        const int node = n0 + m;
        unsigned short* row = As + m * KSU;
        if (node < N_NODES) {
            const uint4* ph = (const uint4*)(hb_in + (size_t)node * 128);
            uint4* d0 = (uint4*)row;
#pragma unroll
            for (int i = 0; i < 4; i++) d0[q * 4 + i] = ph[q * 4 + i];
            const int cntv = hist[node];
            if (q == 0) sF[m] = (cntv > 0) ? 1.f : 0.f;
            const float rden = 1.0f / fmaxf((float)cntv, 1.0f);
            const float4* pa = (const float4*)(aggr + (size_t)node * 128 + q * 32);
            ushort4* d1 = (ushort4*)(row + 128 + q * 32);
#pragma unroll
            for (int i = 0; i < 8; i++) {
                float4 v = pa[i];
                d1[i] = make_ushort4(f2b(v.x * rden), f2b(v.y * rden),
                                     f2b(v.z * rden), f2b(v.w * rden));
            }
            if (q == 0) { uint4 z{0, 0, 0, 0}; ((uint4*)(row + 256))[0] = z; }
        } else {
            if (q == 0) sF[m] = 0.f;
            uint4 z{0, 0, 0, 0};
            uint4* d = (uint4*)row;
            for (int i = q; i < 33; i += 4) d[i] = z;
        }
    }
    __syncthreads();

    const int wv = t >> 6, lane = t & 63, lr = lane & 15, lq = lane >> 4;
    const int cb = wv * 32;
    const f32x4 z4 = {0.f, 0.f, 0.f, 0.f};

    f32x4 acc[4][2];
#pragma unroll
    for (int i = 0; i < 4; i++) { acc[i][0] = z4; acc[i][1] = z4; }
    gemm_2x4<8, KSU, KSU>(As + lr * KSU + lq * 8,
                          u1t + (size_t)(cb + lr) * KSU + lq * 8, acc);
    __syncthreads();

#pragma unroll
    for (int ct = 0; ct < 2; ct++) {
        const int col = cb + ct * 16 + lr;
        const float bv = b1[col];
        const float bfv = bf[col];
#pragma unroll
        for (int rt = 0; rt < 4; rt++) {
#pragma unroll
            for (int r = 0; r < 4; r++) {
                const int ml = rt * 16 + lq * 4 + r;
                float v = fmaxf(acc[rt][ct][r] + bv + sF[ml] * bfv, 0.f);
                As[ml * KSU + col] = f2b(v);
            }
        }
    }
    __syncthreads();

    f32x4 acc2[4][2];
#pragma unroll
    for (int i = 0; i < 4; i++) { acc2[i][0] = z4; acc2[i][1] = z4; }
    gemm_2x4<4, KSU, KS2>(As + lr * KSU + lq * 8,
                          u2t + (size_t)(cb + lr) * KS2 + lq * 8, acc2);
    __syncthreads();

    // residual add into LN staging fp32 [64][132]
#pragma unroll
    for (int ct = 0; ct < 2; ct++) {
        const int col = cb + ct * 16 + lr;
        const float bv = b2[col];
#pragma unroll
        for (int rt = 0; rt < 4; rt++) {
#pragma unroll
            for (int r = 0; r < 4; r++) {
                const int ml = rt * 16 + lq * 4 + r;
                const int node = n0 + ml;
                if (node < N_NODES)
                    LNb[ml * 132 + col] = acc2[rt][ct][r] + bv + h_in[(size_t)node * 128 + col];
            }
        }
    }
    __syncthreads();

    {   // LayerNorm: 4 threads per row
        const int r = t >> 2, c0 = (t & 3) * 32;
        const int node = n0 + r;
        if (node < N_NODES) {
            float s = 0.f, ss = 0.f;
#pragma unroll
            for (int i = 0; i < 32; i++) { float v = LNb[r * 132 + c0 + i]; s += v; ss += v * v; }
            s += __shfl_xor(s, 1); ss += __shfl_xor(ss, 1);
            s += __shfl_xor(s, 2); ss += __shfl_xor(ss, 2);
            const float mu = s * (1.0f / 128.0f);
            const float var = ss * (1.0f / 128.0f) - mu * mu;
            const float rs = rsqrtf(var + 1e-5f);
#pragma unroll
            for (int i = 0; i < 32; i++) {
                const int j = c0 + i;
                float v = (LNb[r * 132 + j] - mu) * rs * g[j] + bet[j];
                h_out[(size_t)node * 128 + j] = v;
                hb_out[(size_t)node * 128 + j] = f2b(v);
            }
        }
    }
}

// ---------------- head GEMM ----------------
__global__ __launch_bounds__(256, 2) void head_kernel(
        const unsigned short* __restrict__ hb, const unsigned short* __restrict__ ht,
        const float* __restrict__ hbias, float* __restrict__ out) {
    __shared__ __align__(16) unsigned short As[64 * KS2];
    const int t = threadIdx.x;
    const int n0 = blockIdx.x * 64;
    {
        const int m = t >> 2, q = t & 3;
        const int node = n0 + m;
        uint4* dst = (uint4*)(As + m * KS2);
        if (node < N_NODES) {
            const uint4* s = (const uint4*)(hb + (size_t)node * 128);
#pragma unroll
            for (int i = 0; i < 4; i++) dst[q * 4 + i] = s[q * 4 + i];
        } else {
            uint4 z{0, 0, 0, 0};
            for (int i = q; i < 16; i += 4) dst[i] = z;
        }
    }
    __syncthreads();

    const int wv = t >> 6, lane = t & 63, lr = lane & 15, lq = lane >> 4;
    const int m0 = wv * 16;
    const f32x4 z4 = {0.f, 0.f, 0.f, 0.f};
    f32x4 acc[8];
#pragma unroll
    for (int i = 0; i < 8; i++) acc[i] = z4;
    gemm8<4, KS2>(As + (m0 + lr) * KS2 + lq * 8, ht + (size_t)lr * KS2 + lq * 8, acc);
#pragma unroll
    for (int ct = 0; ct < 8; ct++) {
        const int col = ct * 16 + lr;
        const float bv = hbias[col];
#pragma unroll
        for (int r = 0; r < 4; r++) {
            const int node = n0 + m0 + lq * 4 + r;
            if (node < N_NODES) out[(size_t)node * 128 + col] = acc[ct][r] + bv;
        }
    }
}

extern "C" void kernel_launch(void* const* d_in, const int* in_sizes, int n_in,
                              void* d_out, int out_size, void* d_ws, size_t ws_size,
                              hipStream_t stream) {
    const float* x       = (const float*)d_in[0];
    const int*   ei      = (const int*)d_in[1];
    const float* ea      = (const float*)d_in[2];
    const float* encW    = (const float*)d_in[3];
    const float* encb    = (const float*)d_in[4];
    const float* encg    = (const float*)d_in[5];
    const float* encbeta = (const float*)d_in[6];
    const float* msgW1   = (const float*)d_in[7];
    const float* msgb1   = (const float*)d_in[8];
    const float* msgW2   = (const float*)d_in[9];
    const float* msgb2   = (const float*)d_in[10];
    const float* updW1   = (const float*)d_in[11];
    const float* updb1   = (const float*)d_in[12];
    const float* updW2   = (const float*)d_in[13];
    const float* updb2   = (const float*)d_in[14];
    const float* lng     = (const float*)d_in[15];
    const float* lnbeta  = (const float*)d_in[16];
    const float* headW   = (const float*)d_in[17];
    const float* headb   = (const float*)d_in[18];

    char* w = (char*)d_ws;
    size_t off = 0;
    auto nxt = [&](size_t bytes) -> void* {
        void* p = w + off;
        off = (off + bytes + 255) & ~(size_t)255;
        return p;
    };
    float*          h     = (float*)nxt((size_t)N_NODES * 128 * 4);
    unsigned short* hb    = (unsigned short*)nxt((size_t)N_NODES * 128 * 2);
    float*          aggr  = (float*)nxt((size_t)N_NODES * 128 * 4);
    unsigned short* Tb    = (unsigned short*)nxt((size_t)N_NODES * 128 * 2);
    unsigned short* Sb    = (unsigned short*)nxt((size_t)N_NODES * 128 * 2);
    unsigned short* eabS  = (unsigned short*)nxt((size_t)N_EDGES * 16 * 2);
    unsigned short* sSrc  = (unsigned short*)nxt((size_t)N_EDGES * 2);
    unsigned short* sTgtS = (unsigned short*)nxt((size_t)N_EDGES * 2);
    int*            hist  = (int*)nxt((size_t)N_NODES * 4);
    int*            incl  = (int*)nxt((size_t)N_NODES * 4);   // becomes cursor
    int*            blksum= (int*)nxt(256 * 4);
    unsigned short* wab   = (unsigned short*)nxt((size_t)NL * 256 * 136 * 2);
    unsigned short* w1cp  = (unsigned short*)nxt((size_t)NL * 128 * 32 * 2);
    unsigned short* u1t   = (unsigned short*)nxt((size_t)NL * 128 * KSU * 2);
    unsigned short* u2t   = (unsigned short*)nxt((size_t)NL * 128 * KS2 * 2);
    unsigned short* ht    = (unsigned short*)nxt((size_t)128 * KS2 * 2);
    float*          bfold = (float*)nxt((size_t)NL * 128 * 4);

    const int NBLK = (N_NODES + 255) / 256;   // 196
    const int PREP_N = NL * 256 * 136 + NL * 128 * 32 + NL * 128 * KSU
                     + NL * 128 * KS2 + 128 * KS2;

    hipMemsetAsync(hist, 0, (size_t)N_NODES * 4, stream);
    prep_kernel<<<(PREP_N + 255) / 256, 256, 0, stream>>>(msgW1, updW1, updW2, headW,
                                                          wab, w1cp, u1t, u2t, ht);
    prep2_kernel<<<NL * 128, 128, 0, stream>>>(msgW2, updW1, u1t);
    prep3_kernel<<<NL, 128, 0, stream>>>(msgb2, updW1, bfold);
    enc_kernel<<<25000, 256, 0, stream>>>(x, encW, encb, encg, encbeta, h, hb);
    hist_kernel<<<3125, 256, 0, stream>>>(ei + N_EDGES, hist);
    scan1_kernel<<<NBLK, 256, 0, stream>>>(hist, incl, blksum);
    scan2_kernel<<<1, 256, 0, stream>>>(blksum, NBLK);
    scan3_kernel<<<NBLK, 256, 0, stream>>>(incl, blksum, hist);
    scatter_kernel<<<3125, 256, 0, stream>>>(ei, ei + N_EDGES, ea, incl,
                                             sSrc, sTgtS, eabS);

    for (int l = 0; l < NL; l++) {
        node_kernel<<<782, 256, 0, stream>>>(hb, wab + (size_t)l * 256 * 136,
                                             msgb1 + l * 128, Tb, Sb);
        hipMemsetAsync(aggr, 0, (size_t)N_NODES * 128 * 4, stream);
        edge_kernel<<<6250, 256, 0, stream>>>(eabS, sSrc, sTgtS,
                                              w1cp + (size_t)l * 128 * 32,
                                              Tb, Sb, aggr);
        upd_kernel<<<782, 256, 0, stream>>>(hb, h, aggr, hist,
                                            u1t + (size_t)l * 128 * KSU,
                                            u2t + (size_t)l * 128 * KS2,
                                            updb1 + l * 128, bfold + l * 128,
                                            updb2 + l * 128,
                                            lng + l * 128, lnbeta + l * 128, h, hb);
    }
    head_kernel<<<782, 256, 0, stream>>>(hb, ht, headb, (float*)d_out);
}

// Round 6
// 576.660 us; speedup vs baseline: 1.1840x; 1.0117x over previous
//
#include <hip/hip_runtime.h>
#include <hip/hip_bf16.h>
#include <stdint.h>

#define N_NODES 50000
#define N_EDGES 800000
#define NL 2

// K strides (bf16 elements)
#define KS2 136   // 128-K GEMMs: 4 k-steps, stride 136
#define KSU 264   // upd GEMM1: K=256 (8 k-steps), stride 264
#define ESTR 133  // edge_kernel fp32 LDS stride: bank=(5m+c)%32, conflict-free

typedef __bf16 bf16x8 __attribute__((ext_vector_type(8)));
typedef float f32x4 __attribute__((ext_vector_type(4)));

__device__ __forceinline__ f32x4 mfma_bf16(uint4 a, uint4 b, f32x4 c) {
    return __builtin_amdgcn_mfma_f32_16x16x32_bf16(
        __builtin_bit_cast(bf16x8, a), __builtin_bit_cast(bf16x8, b), c, 0, 0, 0);
}

__device__ __forceinline__ unsigned short f2b(float f) {
    union { float f; unsigned u; } v; v.f = f;
    unsigned r = v.u + 0x7FFFu + ((v.u >> 16) & 1u);   // RNE
    return (unsigned short)(r >> 16);
}

__device__ __forceinline__ float b2f(unsigned short u) {
    union { unsigned u; float f; } v; v.u = ((unsigned)u) << 16; return v.f;
}
__device__ __forceinline__ float b2f_lo(unsigned u) {
    union { unsigned u; float f; } v; v.u = u << 16; return v.f;
}
__device__ __forceinline__ float b2f_hi(unsigned u) {
    union { unsigned u; float f; } v; v.u = u & 0xFFFF0000u; return v.f;
}

// Per-wave 16-row x 128-col tile (head_kernel).
template<int KSTEPS, int BSTR>
__device__ __forceinline__ void gemm8(const unsigned short* aLane,
                                      const unsigned short* bLane, f32x4 acc[8]) {
#pragma unroll
    for (int kc = 0; kc < KSTEPS; kc++) {
        uint4 a = *(const uint4*)(aLane + kc * 32);
#pragma unroll
        for (int ct = 0; ct < 8; ct++) {
            uint4 b = *(const uint4*)(bLane + (size_t)ct * 16 * BSTR + kc * 32);
            acc[ct] = mfma_bf16(a, b, acc[ct]);
        }
    }
}

// Column-split wave tile: 64 rows (4 rt) x 32 cols (2 ct) per wave (upd_kernel).
template<int KSTEPS, int ASTR, int BSTR>
__device__ __forceinline__ void gemm_2x4(const unsigned short* aLane,
                                         const unsigned short* bLane,
                                         f32x4 acc[4][2]) {
#pragma unroll
    for (int kc = 0; kc < KSTEPS; kc++) {
        uint4 b0 = *(const uint4*)(bLane + kc * 32);
        uint4 b1 = *(const uint4*)(bLane + (size_t)16 * BSTR + kc * 32);
#pragma unroll
        for (int rt = 0; rt < 4; rt++) {
            uint4 a = *(const uint4*)(aLane + (size_t)rt * 16 * ASTR + kc * 32);
            acc[rt][0] = mfma_bf16(a, b0, acc[rt][0]);
            acc[rt][1] = mfma_bf16(a, b1, acc[rt][1]);
        }
    }
}

// ---------------- weight prep ----------------
__global__ void prep_kernel(const float* __restrict__ mW1,
                            const float* __restrict__ uW1, const float* __restrict__ uW2,
                            const float* __restrict__ hW,
                            unsigned short* __restrict__ wab, unsigned short* __restrict__ w1cp,
                            unsigned short* __restrict__ u1t, unsigned short* __restrict__ u2t,
                            unsigned short* __restrict__ ht) {
    int i = blockIdx.x * 256 + threadIdx.x;
    const int SA = NL * 256 * 136;
    const int SC = NL * 128 * 32;
    const int SU = NL * 128 * KSU;
    const int S3 = NL * 128 * KS2;
    const int S4 = 128 * KS2;
    if (i < SA) {
        int l = i / (256 * 136), r = i % (256 * 136), j = r / 136, k = r % 136;
        float v = 0.f;
        if (k < 128)
            v = (j < 128) ? mW1[((size_t)l * 272 + k) * 128 + j]
                          : mW1[((size_t)l * 272 + 128 + k) * 128 + (j - 128)];
        wab[i] = f2b(v);
        return;
    }
    i -= SA;
    if (i < SC) {
        int l = i / (128 * 32), r = i % (128 * 32), j = r / 32, k = r % 32;
        w1cp[i] = (k < 16) ? f2b(mW1[((size_t)l * 272 + 256 + k) * 128 + j]) : (unsigned short)0;
        return;
    }
    i -= SC;
    if (i < SU) {
        int l = i / (128 * KSU), r = i % (128 * KSU), n = r / KSU, k = r % KSU;
        if (k < 128)       u1t[i] = f2b(uW1[((size_t)l * 256 + k) * 128 + n]);
        else if (k >= 256) u1t[i] = 0;
        return;
    }
    i -= SU;
    if (i < S3) {
        int l = i / (128 * KS2), r = i % (128 * KS2), n = r / KS2, k = r % KS2;
        u2t[i] = (k < 128) ? f2b(uW2[((size_t)l * 128 + k) * 128 + n]) : (unsigned short)0;
        return;
    }
    i -= S3;
    if (i < S4) {
        int n = i / KS2, k = i % KS2;
        ht[i] = (k < 128) ? f2b(hW[(size_t)k * 128 + n]) : (unsigned short)0;
    }
}

// ---------------- prep2: u1t[l][n][128+j] = bf16( sum_c W2[l][j][c] * U1[l][128+c][n] )
__global__ void prep2_kernel(const float* __restrict__ mW2, const float* __restrict__ uW1,
                             unsigned short* __restrict__ u1t) {
    __shared__ float w2row[128];
    const int l = blockIdx.x >> 7, j = blockIdx.x & 127;
    const int n = threadIdx.x;
    w2row[n] = mW2[((size_t)l * 128 + j) * 128 + n];
    __syncthreads();
    float s = 0.f;
#pragma unroll 8
    for (int c = 0; c < 128; c++)
        s += w2row[c] * uW1[((size_t)l * 256 + 128 + c) * 128 + n];
    u1t[(size_t)l * 128 * KSU + (size_t)n * KSU + 128 + j] = f2b(s);
}

// ---------------- prep3: bfold[l][n] = sum_c b2[l][c] * U1[l][128+c][n]
__global__ void prep3_kernel(const float* __restrict__ mb2, const float* __restrict__ uW1,
                             float* __restrict__ bfold) {
    const int l = blockIdx.x;
    const int n = threadIdx.x;
    float s = 0.f;
#pragma unroll 8
    for (int c = 0; c < 128; c++)
        s += mb2[l * 128 + c] * uW1[((size_t)l * 256 + 128 + c) * 128 + n];
    bfold[l * 128 + n] = s;
}

// ---------------- encoder: relu(x@W+b) -> LN ----------------
__global__ __launch_bounds__(256) void enc_kernel(
        const float* __restrict__ x, const float* __restrict__ W,
        const float* __restrict__ b, const float* __restrict__ g, const float* __restrict__ bet,
        float* __restrict__ h, unsigned short* __restrict__ hb) {
    __shared__ float sx[64];
    __shared__ float redS[4], redSS[4];
    const int t = threadIdx.x;
    const int nb = blockIdx.x * 2;           // 2 nodes / block; 25000 blocks exact
    if (t < 64) sx[t] = x[(size_t)nb * 32 + t];
    __syncthreads();
    const int half = t >> 7, j = t & 127;
    const int node = nb + half;
    float acc = b[j];
#pragma unroll
    for (int k = 0; k < 32; k++) acc += sx[half * 32 + k] * W[k * 128 + j];
    float v = fmaxf(acc, 0.f);
    float s = v, ss = v * v;
#pragma unroll
    for (int d = 32; d > 0; d >>= 1) { s += __shfl_down(s, d); ss += __shfl_down(ss, d); }
    const int wv = t >> 6;
    if ((t & 63) == 0) { redS[wv] = s; redSS[wv] = ss; }
    __syncthreads();
    float S = redS[half * 2] + redS[half * 2 + 1];
    float SS = redSS[half * 2] + redSS[half * 2 + 1];
    float mu = S * (1.f / 128.f);
    float var = SS * (1.f / 128.f) - mu * mu;
    float rs = rsqrtf(var + 1e-5f);
    float o = (v - mu) * rs * g[j] + bet[j];
    h[(size_t)node * 128 + j] = o;
    hb[(size_t)node * 128 + j] = f2b(o);
}

// ---------------- counting sort of edges by target ----------------
__global__ void hist_kernel(const int* __restrict__ tgt, int* __restrict__ hist) {
    int i = blockIdx.x * 256 + threadIdx.x;   // E = 3125*256 exact
    atomicAdd(hist + tgt[i], 1);
}

__global__ void scan1_kernel(const int* __restrict__ hist, int* __restrict__ incl,
                             int* __restrict__ blksum) {
    __shared__ int buf[256];
    const int t = threadIdx.x;
    const int i = blockIdx.x * 256 + t;
    int v = (i < N_NODES) ? hist[i] : 0;
    buf[t] = v; __syncthreads();
#pragma unroll
    for (int d = 1; d < 256; d <<= 1) {
        int x = (t >= d) ? buf[t - d] : 0;
        __syncthreads();
        buf[t] += x;
        __syncthreads();
    }
    if (i < N_NODES) incl[i] = buf[t];
    if (t == 255) blksum[blockIdx.x] = buf[255];
}

__global__ void scan2_kernel(int* __restrict__ blksum, int nblk) {
    __shared__ int buf[256];
    const int t = threadIdx.x;
    int v = (t < nblk) ? blksum[t] : 0;
    buf[t] = v; __syncthreads();
#pragma unroll
    for (int d = 1; d < 256; d <<= 1) {
        int x = (t >= d) ? buf[t - d] : 0;
        __syncthreads();
        buf[t] += x;
        __syncthreads();
    }
    if (t < nblk) blksum[t] = buf[t];
}

__global__ void scan3_kernel(int* __restrict__ incl, const int* __restrict__ blksum,
                             const int* __restrict__ hist) {
    const int i = blockIdx.x * 256 + threadIdx.x;
    if (i >= N_NODES) return;
    const int b = blockIdx.x;
    const int base = (b > 0) ? blksum[b - 1] : 0;
    incl[i] = incl[i] + base - hist[i];
}

__global__ void scatter_kernel(const int* __restrict__ src, const int* __restrict__ tgt,
                               const float* __restrict__ ea, int* __restrict__ cursor,
                               unsigned short* __restrict__ sSrc, unsigned short* __restrict__ sTgt,
                               unsigned short* __restrict__ eabS) {
    const int e = blockIdx.x * 256 + threadIdx.x;   // E exact
    const int tg = tgt[e];
    const int p = atomicAdd(cursor + tg, 1);
    sSrc[p] = (unsigned short)src[e];
    sTgt[p] = (unsigned short)tg;
    const float4* s = (const float4*)(ea + (size_t)e * 16);
    ushort4* d = (ushort4*)(eabS + (size_t)p * 16);
#pragma unroll
    for (int i = 0; i < 4; i++) {
        float4 v = s[i];
        d[i] = make_ushort4(f2b(v.x), f2b(v.y), f2b(v.z), f2b(v.w));
    }
}

// ---------------- per-layer node GEMM: T = h@W1a + b1, S = h@W1b ----------------
__global__ __launch_bounds__(256, 4) void node_kernel(
        const unsigned short* __restrict__ hb, const unsigned short* __restrict__ wab,
        const float* __restrict__ b1,
        unsigned short* __restrict__ Tb, unsigned short* __restrict__ Sb) {
    __shared__ __align__(16) unsigned short As[64 * KS2];
    const int t = threadIdx.x;
    const int n0 = blockIdx.x * 64;
    {
        const int m = t >> 2, q = t & 3;
        const int node = n0 + m;
        uint4* dst = (uint4*)(As + m * KS2);
        if (node < N_NODES) {
            const uint4* s = (const uint4*)(hb + (size_t)node * 128);
#pragma unroll
            for (int i = 0; i < 4; i++) dst[q * 4 + i] = s[q * 4 + i];
        } else {
            uint4 z{0, 0, 0, 0};
            for (int i = q; i < 16; i += 4) dst[i] = z;
        }
    }
    __syncthreads();

    const int wv = t >> 6, lane = t & 63, lr = lane & 15, lq = lane >> 4;
    const int cb = wv * 64;
    const f32x4 z4 = {0.f, 0.f, 0.f, 0.f};
    f32x4 acc[4][4];                     // [rt][ct]
#pragma unroll
    for (int i = 0; i < 4; i++)
#pragma unroll
        for (int j = 0; j < 4; j++) acc[i][j] = z4;

    const unsigned short* aL = As + lr * KS2 + lq * 8;
    const unsigned short* bL = wab + (size_t)(cb + lr) * KS2 + lq * 8;
#pragma unroll
    for (int kc = 0; kc < 4; kc++) {
        uint4 bA = *(const uint4*)(bL + kc * 32);
        uint4 bB = *(const uint4*)(bL + (size_t)16 * KS2 + kc * 32);
        uint4 bC = *(const uint4*)(bL + (size_t)32 * KS2 + kc * 32);
        uint4 bD = *(const uint4*)(bL + (size_t)48 * KS2 + kc * 32);
#pragma unroll
        for (int rt = 0; rt < 4; rt++) {
            uint4 a = *(const uint4*)(aL + (size_t)rt * 16 * KS2 + kc * 32);
            acc[rt][0] = mfma_bf16(a, bA, acc[rt][0]);
            acc[rt][1] = mfma_bf16(a, bB, acc[rt][1]);
            acc[rt][2] = mfma_bf16(a, bC, acc[rt][2]);
            acc[rt][3] = mfma_bf16(a, bD, acc[rt][3]);
        }
    }
#pragma unroll
    for (int ct = 0; ct < 4; ct++) {
        const int j = cb + ct * 16 + lr;
        const float bias = (j < 128) ? b1[j] : 0.f;
#pragma unroll
        for (int rt = 0; rt < 4; rt++) {
#pragma unroll
            for (int r = 0; r < 4; r++) {
                const int node = n0 + rt * 16 + lq * 4 + r;
                if (node < N_NODES) {
                    const float v = acc[rt][ct][r] + bias;
                    if (j < 128) Tb[(size_t)node * 128 + j] = f2b(v);
                    else         Sb[(size_t)node * 128 + (j - 128)] = f2b(v);
                }
            }
        }
    }
}

// ---------------- edge kernel: relu(T[tgt]+S[src]+ea@W1c) + segmented sum ----------------
// 64 edges/block, 12500 blocks. Three phases on fp32 LDS Es[64][ESTR]:
//  P1: per-wave MFMA (ea@W1c), raw fp32 acc -> Es (C-layout scatter, no conv).
//  P2: thread = one edge x 4 col-chunks; uint4 vector gathers of Tb/Sb rows;
//      Es += T+S, relu, in place.
//  P3: segmented fp32 sum over sorted targets, one atomic per run x col.
__global__ __launch_bounds__(256, 4) void edge_kernel(
        const unsigned short* __restrict__ eabS,
        const unsigned short* __restrict__ sSrc, const unsigned short* __restrict__ sTgt,
        const unsigned short* __restrict__ w1cp,
        const unsigned short* __restrict__ Tb, const unsigned short* __restrict__ Sb,
        float* __restrict__ aggr) {
    __shared__ float Es[64 * ESTR];
    __shared__ int sT[64];
    __shared__ int sS[64];

    const int t = threadIdx.x;
    const int e0 = blockIdx.x * 64;          // E = 12500*64 exact
    if (t < 64) { sT[t] = sTgt[e0 + t]; sS[t] = sSrc[e0 + t]; }

    const int wv = t >> 6, lane = t & 63, lr = lane & 15, lq = lane >> 4;
    const f32x4 z4 = {0.f, 0.f, 0.f, 0.f};
    {   // Phase 1: wave wv owns row-tile wv (16 edges)
        uint4 a = {0, 0, 0, 0};
        if (lq < 2) a = *(const uint4*)(eabS + (size_t)(e0 + wv * 16 + lr) * 16 + lq * 8);
        f32x4 acc[8];
#pragma unroll
        for (int ct = 0; ct < 8; ct++) {
            uint4 b = *(const uint4*)(w1cp + (ct * 16 + lr) * 32 + lq * 8);
            acc[ct] = mfma_bf16(a, b, z4);
        }
#pragma unroll
        for (int ct = 0; ct < 8; ct++) {
            const int col = ct * 16 + lr;
#pragma unroll
            for (int r = 0; r < 4; r++)
                Es[(wv * 16 + lq * 4 + r) * ESTR + col] = acc[ct][r];
        }
    }
    __syncthreads();

    {   // Phase 2: thread -> edge m = t&63, chunks c8 = (t>>6) + {0,4,8,12}
        const int m = t & 63;
        const int c8b = t >> 6;
        const unsigned short* Trow = Tb + (size_t)sT[m] * 128;
        const unsigned short* Srow = Sb + (size_t)sS[m] * 128;
        float* Erow = Es + m * ESTR;
#pragma unroll
        for (int it = 0; it < 4; it++) {
            const int c0 = (c8b + it * 4) * 8;
            const uint4 tv = *(const uint4*)(Trow + c0);
            const uint4 sv = *(const uint4*)(Srow + c0);
            float tf[8] = {b2f_lo(tv.x), b2f_hi(tv.x), b2f_lo(tv.y), b2f_hi(tv.y),
                           b2f_lo(tv.z), b2f_hi(tv.z), b2f_lo(tv.w), b2f_hi(tv.w)};
            float sf[8] = {b2f_lo(sv.x), b2f_hi(sv.x), b2f_lo(sv.y), b2f_hi(sv.y),
                           b2f_lo(sv.z), b2f_hi(sv.z), b2f_lo(sv.w), b2f_hi(sv.w)};
#pragma unroll
            for (int i = 0; i < 8; i++)
                Erow[c0 + i] = fmaxf(Erow[c0 + i] + tf[i] + sf[i], 0.f);
        }
    }
    __syncthreads();

    {   // Phase 3: segmented sum, 2 threads/col (32-row halves)
        const int c = t >> 1;
        const int rb = (t & 1) * 32;
        float s = 0.f;
        int cur = sT[rb];
        for (int i = 0; i < 32; i++) {
            const int rg = rb + i;
            const int tg = sT[rg];
            if (tg != cur) {
                atomicAdd(aggr + (size_t)cur * 128 + c, s);
                s = 0.f; cur = tg;
            }
            s += Es[rg * ESTR + c];
        }
        atomicAdd(aggr + (size_t)cur * 128 + c, s);
    }
}

// ---------------- update MLP + residual + LN ----------------
__global__ __launch_bounds__(256, 4) void upd_kernel(
        const unsigned short* __restrict__ hb_in, const float* __restrict__ h_in,
        const float* __restrict__ aggr, const int* __restrict__ hist,
        const unsigned short* __restrict__ u1t, const unsigned short* __restrict__ u2t,
        const float* __restrict__ b1, const float* __restrict__ bf,
        const float* __restrict__ b2,
        const float* __restrict__ g, const float* __restrict__ bet,
        float* __restrict__ h_out, unsigned short* __restrict__ hb_out) {
    __shared__ __align__(16) char smemA[64 * KSU * 2];
    __shared__ float sF[64];
    unsigned short* As = (unsigned short*)smemA;
    float* LNb = (float*)smemA;

    const int t = threadIdx.x;
    const int n0 = blockIdx.x * 64;
    {
        const int m = t >> 2, q = t & 3;
        const int node = n0 + m;
        unsigned short* row = As + m * KSU;
        if (node < N_NODES) {
            const uint4* ph = (const uint4*)(hb_in + (size_t)node * 128);
            uint4* d0 = (uint4*)row;
#pragma unroll
            for (int i = 0; i < 4; i++) d0[q * 4 + i] = ph[q * 4 + i];
            const int cntv = hist[node];
            if (q == 0) sF[m] = (cntv > 0) ? 1.f : 0.f;
            const float rden = 1.0f / fmaxf((float)cntv, 1.0f);
            const float4* pa = (const float4*)(aggr + (size_t)node * 128 + q * 32);
            ushort4* d1 = (ushort4*)(row + 128 + q * 32);
#pragma unroll
            for (int i = 0; i < 8; i++) {
                float4 v = pa[i];
                d1[i] = make_ushort4(f2b(v.x * rden), f2b(v.y * rden),
                                     f2b(v.z * rden), f2b(v.w * rden));
            }
            if (q == 0) { uint4 z{0, 0, 0, 0}; ((uint4*)(row + 256))[0] = z; }
        } else {
            if (q == 0) sF[m] = 0.f;
            uint4 z{0, 0, 0, 0};
            uint4* d = (uint4*)row;
            for (int i = q; i < 33; i += 4) d[i] = z;
        }
    }
    __syncthreads();

    const int wv = t >> 6, lane = t & 63, lr = lane & 15, lq = lane >> 4;
    const int cb = wv * 32;
    const f32x4 z4 = {0.f, 0.f, 0.f, 0.f};

    f32x4 acc[4][2];
#pragma unroll
    for (int i = 0; i < 4; i++) { acc[i][0] = z4; acc[i][1] = z4; }
    gemm_2x4<8, KSU, KSU>(As + lr * KSU + lq * 8,
                          u1t + (size_t)(cb + lr) * KSU + lq * 8, acc);
    __syncthreads();

#pragma unroll
    for (int ct = 0; ct < 2; ct++) {
        const int col = cb + ct * 16 + lr;
        const float bv = b1[col];
        const float bfv = bf[col];
#pragma unroll
        for (int rt = 0; rt < 4; rt++) {
#pragma unroll
            for (int r = 0; r < 4; r++) {
                const int ml = rt * 16 + lq * 4 + r;
                float v = fmaxf(acc[rt][ct][r] + bv + sF[ml] * bfv, 0.f);
                As[ml * KSU + col] = f2b(v);
            }
        }
    }
    __syncthreads();

    f32x4 acc2[4][2];
#pragma unroll
    for (int i = 0; i < 4; i++) { acc2[i][0] = z4; acc2[i][1] = z4; }
    gemm_2x4<4, KSU, KS2>(As + lr * KSU + lq * 8,
                          u2t + (size_t)(cb + lr) * KS2 + lq * 8, acc2);
    __syncthreads();

    // residual add into LN staging fp32 [64][132]
#pragma unroll
    for (int ct = 0; ct < 2; ct++) {
        const int col = cb + ct * 16 + lr;
        const float bv = b2[col];
#pragma unroll
        for (int rt = 0; rt < 4; rt++) {
#pragma unroll
            for (int r = 0; r < 4; r++) {
                const int ml = rt * 16 + lq * 4 + r;
                const int node = n0 + ml;
                if (node < N_NODES)
                    LNb[ml * 132 + col] = acc2[rt][ct][r] + bv + h_in[(size_t)node * 128 + col];
            }
        }
    }
    __syncthreads();

    {   // LayerNorm: 4 threads per row
        const int r = t >> 2, c0 = (t & 3) * 32;
        const int node = n0 + r;
        if (node < N_NODES) {
            float s = 0.f, ss = 0.f;
#pragma unroll
            for (int i = 0; i < 32; i++) { float v = LNb[r * 132 + c0 + i]; s += v; ss += v * v; }
            s += __shfl_xor(s, 1); ss += __shfl_xor(ss, 1);
            s += __shfl_xor(s, 2); ss += __shfl_xor(ss, 2);
            const float mu = s * (1.0f / 128.0f);
            const float var = ss * (1.0f / 128.0f) - mu * mu;
            const float rs = rsqrtf(var + 1e-5f);
#pragma unroll
            for (int i = 0; i < 32; i++) {
                const int j = c0 + i;
                float v = (LNb[r * 132 + j] - mu) * rs * g[j] + bet[j];
                h_out[(size_t)node * 128 + j] = v;
                hb_out[(size_t)node * 128 + j] = f2b(v);
            }
        }
    }
}

// ---------------- head GEMM ----------------
__global__ __launch_bounds__(256, 2) void head_kernel(
        const unsigned short* __restrict__ hb, const unsigned short* __restrict__ ht,
        const float* __restrict__ hbias, float* __restrict__ out) {
    __shared__ __align__(16) unsigned short As[64 * KS2];
    const int t = threadIdx.x;
    const int n0 = blockIdx.x * 64;
    {
        const int m = t >> 2, q = t & 3;
        const int node = n0 + m;
        uint4* dst = (uint4*)(As + m * KS2);
        if (node < N_NODES) {
            const uint4* s = (const uint4*)(hb + (size_t)node * 128);
#pragma unroll
            for (int i = 0; i < 4; i++) dst[q * 4 + i] = s[q * 4 + i];
        } else {
            uint4 z{0, 0, 0, 0};
            for (int i = q; i < 16; i += 4) dst[i] = z;
        }
    }
    __syncthreads();

    const int wv = t >> 6, lane = t & 63, lr = lane & 15, lq = lane >> 4;
    const int m0 = wv * 16;
    const f32x4 z4 = {0.f, 0.f, 0.f, 0.f};
    f32x4 acc[8];
#pragma unroll
    for (int i = 0; i < 8; i++) acc[i] = z4;
    gemm8<4, KS2>(As + (m0 + lr) * KS2 + lq * 8, ht + (size_t)lr * KS2 + lq * 8, acc);
#pragma unroll
    for (int ct = 0; ct < 8; ct++) {
        const int col = ct * 16 + lr;
        const float bv = hbias[col];
#pragma unroll
        for (int r = 0; r < 4; r++) {
            const int node = n0 + m0 + lq * 4 + r;
            if (node < N_NODES) out[(size_t)node * 128 + col] = acc[ct][r] + bv;
        }
    }
}

extern "C" void kernel_launch(void* const* d_in, const int* in_sizes, int n_in,
                              void* d_out, int out_size, void* d_ws, size_t ws_size,
                              hipStream_t stream) {
    const float* x       = (const float*)d_in[0];
    const int*   ei      = (const int*)d_in[1];
    const float* ea      = (const float*)d_in[2];
    const float* encW    = (const float*)d_in[3];
    const float* encb    = (const float*)d_in[4];
    const float* encg    = (const float*)d_in[5];
    const float* encbeta = (const float*)d_in[6];
    const float* msgW1   = (const float*)d_in[7];
    const float* msgb1   = (const float*)d_in[8];
    const float* msgW2   = (const float*)d_in[9];
    const float* msgb2   = (const float*)d_in[10];
    const float* updW1   = (const float*)d_in[11];
    const float* updb1   = (const float*)d_in[12];
    const float* updW2   = (const float*)d_in[13];
    const float* updb2   = (const float*)d_in[14];
    const float* lng     = (const float*)d_in[15];
    const float* lnbeta  = (const float*)d_in[16];
    const float* headW   = (const float*)d_in[17];
    const float* headb   = (const float*)d_in[18];

    char* w = (char*)d_ws;
    size_t off = 0;
    auto nxt = [&](size_t bytes) -> void* {
        void* p = w + off;
        off = (off + bytes + 255) & ~(size_t)255;
        return p;
    };
    float*          h     = (float*)nxt((size_t)N_NODES * 128 * 4);
    unsigned short* hb    = (unsigned short*)nxt((size_t)N_NODES * 128 * 2);
    float*          aggr  = (float*)nxt((size_t)N_NODES * 128 * 4);
    unsigned short* Tb    = (unsigned short*)nxt((size_t)N_NODES * 128 * 2);
    unsigned short* Sb    = (unsigned short*)nxt((size_t)N_NODES * 128 * 2);
    unsigned short* eabS  = (unsigned short*)nxt((size_t)N_EDGES * 16 * 2);
    unsigned short* sSrc  = (unsigned short*)nxt((size_t)N_EDGES * 2);
    unsigned short* sTgtS = (unsigned short*)nxt((size_t)N_EDGES * 2);
    int*            hist  = (int*)nxt((size_t)N_NODES * 4);
    int*            incl  = (int*)nxt((size_t)N_NODES * 4);   // becomes cursor
    int*            blksum= (int*)nxt(256 * 4);
    unsigned short* wab   = (unsigned short*)nxt((size_t)NL * 256 * 136 * 2);
    unsigned short* w1cp  = (unsigned short*)nxt((size_t)NL * 128 * 32 * 2);
    unsigned short* u1t   = (unsigned short*)nxt((size_t)NL * 128 * KSU * 2);
    unsigned short* u2t   = (unsigned short*)nxt((size_t)NL * 128 * KS2 * 2);
    unsigned short* ht    = (unsigned short*)nxt((size_t)128 * KS2 * 2);
    float*          bfold = (float*)nxt((size_t)NL * 128 * 4);

    const int NBLK = (N_NODES + 255) / 256;   // 196
    const int PREP_N = NL * 256 * 136 + NL * 128 * 32 + NL * 128 * KSU
                     + NL * 128 * KS2 + 128 * KS2;

    hipMemsetAsync(hist, 0, (size_t)N_NODES * 4, stream);
    prep_kernel<<<(PREP_N + 255) / 256, 256, 0, stream>>>(msgW1, updW1, updW2, headW,
                                                          wab, w1cp, u1t, u2t, ht);
    prep2_kernel<<<NL * 128, 128, 0, stream>>>(msgW2, updW1, u1t);
    prep3_kernel<<<NL, 128, 0, stream>>>(msgb2, updW1, bfold);
    enc_kernel<<<25000, 256, 0, stream>>>(x, encW, encb, encg, encbeta, h, hb);
    hist_kernel<<<3125, 256, 0, stream>>>(ei + N_EDGES, hist);
    scan1_kernel<<<NBLK, 256, 0, stream>>>(hist, incl, blksum);
    scan2_kernel<<<1, 256, 0, stream>>>(blksum, NBLK);
    scan3_kernel<<<NBLK, 256, 0, stream>>>(incl, blksum, hist);
    scatter_kernel<<<3125, 256, 0, stream>>>(ei, ei + N_EDGES, ea, incl,
                                             sSrc, sTgtS, eabS);

    for (int l = 0; l < NL; l++) {
        node_kernel<<<782, 256, 0, stream>>>(hb, wab + (size_t)l * 256 * 136,
                                             msgb1 + l * 128, Tb, Sb);
        hipMemsetAsync(aggr, 0, (size_t)N_NODES * 128 * 4, stream);
        edge_kernel<<<12500, 256, 0, stream>>>(eabS, sSrc, sTgtS,
                                               w1cp + (size_t)l * 128 * 32,
                                               Tb, Sb, aggr);
        upd_kernel<<<782, 256, 0, stream>>>(hb, h, aggr, hist,
                                            u1t + (size_t)l * 128 * KSU,
                                            u2t + (size_t)l * 128 * KS2,
                                            updb1 + l * 128, bfold + l * 128,
                                            updb2 + l * 128,
                                            lng + l * 128, lnbeta + l * 128, h, hb);
    }
    head_kernel<<<782, 256, 0, stream>>>(hb, ht, headb, (float*)d_out);
}